// Round 8
// baseline (240.059 us; speedup 1.0000x reference)
//
#include <hip/hip_runtime.h>
#include <hip/hip_bf16.h>
#include <math.h>

#define NS 32768   // samples
#define NC 1000    // classes
#define CP 1024    // padded classes
#define DD 1024    // feature dim
#define KN 16      // KNN

typedef __attribute__((ext_vector_type(8))) short bf16x8;
typedef __attribute__((ext_vector_type(4))) float f32x4;
typedef __attribute__((ext_vector_type(4))) float float4v;
typedef __attribute__((ext_vector_type(4))) int int4v;
typedef __attribute__((ext_vector_type(8))) unsigned short u16x8;
typedef __attribute__((ext_vector_type(4))) unsigned short u16x4;

__device__ __forceinline__ unsigned short f2bf(float f) {
  unsigned u = __float_as_uint(f);
  u += 0x7FFFu + ((u >> 16) & 1u);          // RNE
  return (unsigned short)(u >> 16);
}
__device__ __forceinline__ float bf2f(unsigned short h) {
  return __uint_as_float(((unsigned)h) << 16);
}

#define GLL16(g, l) __builtin_amdgcn_global_load_lds( \
    (const __attribute__((address_space(1))) void*)(g), \
    (__attribute__((address_space(3))) void*)(l), 16, 0, 0)

// ---------------- cast centroids -> bf16 (padded to 1024 rows) + norms ----
__global__ __launch_bounds__(256) void k_cast_cent(
    const float* __restrict__ Cm, unsigned short* __restrict__ Cb,
    float* __restrict__ cnorm2, float* __restrict__ invc) {
  int c = blockIdx.x;            // 0..1023
  int tid = threadIdx.x;         // 256, each does 4 elems
  float sq = 0.f;
  if (c < NC) {
    float4v v = ((const float4v*)(Cm + (size_t)c * DD))[tid];
    sq = v[0]*v[0] + v[1]*v[1] + v[2]*v[2] + v[3]*v[3];
    u16x4 o = { f2bf(v[0]), f2bf(v[1]), f2bf(v[2]), f2bf(v[3]) };
    *(u16x4*)(Cb + (size_t)c * DD + tid * 4) = o;
  } else {
    u16x4 z = { 0, 0, 0, 0 };
    *(u16x4*)(Cb + (size_t)c * DD + tid * 4) = z;
  }
  for (int off = 32; off; off >>= 1) sq += __shfl_xor(sq, off);
  __shared__ float red[4];
  int lane = tid & 63, wid = tid >> 6;
  if (!lane) red[wid] = sq;
  __syncthreads();
  if (!tid) {
    float s = red[0] + red[1] + red[2] + red[3];
    cnorm2[c] = s;
    float n = sqrtf(s); if (n < 1e-8f) n = 1e-8f;
    invc[c] = (c < NC) ? 1.0f / n : 0.0f;
  }
}

// ---------------- cast feature -> bf16 ------------------------------------
__global__ __launch_bounds__(256) void k_cast_feat(
    const float* __restrict__ A, unsigned short* __restrict__ Ab) {
  int t = blockIdx.x * 256 + threadIdx.x;   // 4,194,304 threads x 8 elems
  const float4v* src = (const float4v*)A + (size_t)t * 2;
  float4v a = src[0], b = src[1];
  u16x8 o = { f2bf(a[0]), f2bf(a[1]), f2bf(a[2]), f2bf(a[3]),
              f2bf(b[0]), f2bf(b[1]), f2bf(b[2]), f2bf(b[3]) };
  *(u16x8*)(Ab + (size_t)t * 8) = o;
}

// ---------------- GEMM: dot[i][c] = sum_k feat[i,k]*cent[c,k]  (bf16) -----
// m201-style phase schedule @ K=1024: 256x256 tile, 16 K-tiles of BK=64,
// 8 waves (2Mx4N), 512 threads. LDS = 2 parity buffers x {A 32K + B 32K}
// = 128 KiB, in 8KB chunks of 128 rows x 32 k. Per tile: 4 phases (kh,mh),
// each = { 8 ds_read_b128 || 2 global_load_lds -> s_barrier -> setprio(1)
// 16 MFMA setprio(0) [vmcnt(4) at P1,P3] -> s_barrier }. Counted-vmcnt
// ledger (2 GLL16/phase): gate@P1 lands this tile's kh1 chunks, gate@P3
// lands next tile's kh0; never drains in main loop; loads get >=4 phases
// to cover latency. Chunk-death: kh0 dies @P1, kh1 @P3; stage targets are
// >=5 barriers dead. T2 granule-XOR swizzle (R7-verified, conflicts=0)
// unchanged on both sides; T1 XCD swizzle; T5 setprio (pays on phased
// schedules, m218b). K-accumulation order bit-identical to R7.
#define MF(a_, b_, c_) __builtin_amdgcn_mfma_f32_16x16x32_bf16(a_, b_, c_, 0, 0, 0)
#define VM4 asm volatile("s_waitcnt vmcnt(4)" ::: "memory")
#define VM0 asm volatile("s_waitcnt vmcnt(0)" ::: "memory")
// stage A (or B) chunks rh=0,1 of (tile t_, k-half kh_) into parity buf
#define SAK(t_, kh_) do { \
    GLL16(gA0 + (t_) * 64 + (kh_) * 32, ldsB + (((t_) & 1) << 16) + ((kh_) * 2 + 0) * 8192 + dst); \
    GLL16(gA1 + (t_) * 64 + (kh_) * 32, ldsB + (((t_) & 1) << 16) + ((kh_) * 2 + 1) * 8192 + dst); } while (0)
#define SBK(t_, kh_) do { \
    GLL16(gB0 + (t_) * 64 + (kh_) * 32, ldsB + (((t_) & 1) << 16) + 32768 + ((kh_) * 2 + 0) * 8192 + dst); \
    GLL16(gB1 + (t_) * 64 + (kh_) * 32, ldsB + (((t_) & 1) << 16) + 32768 + ((kh_) * 2 + 1) * 8192 + dst); } while (0)
#define PHASE(t_, kh_, mh_, STAGE_, GATE_) do { \
    const char* Ab_ = ldsB + (((t_) & 1) << 16) + ((kh_) * 2 + wr) * 8192 + (mh_) * 4096 + aoff; \
    const char* Bb_ = ldsB + (((t_) & 1) << 16) + 32768 + ((kh_) * 2 + (wc >> 1)) * 8192 + (wc & 1) * 4096 + aoff; \
    bf16x8 a0 = *(const bf16x8*)(Ab_); \
    bf16x8 a1 = *(const bf16x8*)(Ab_ + 1024); \
    bf16x8 a2 = *(const bf16x8*)(Ab_ + 2048); \
    bf16x8 a3 = *(const bf16x8*)(Ab_ + 3072); \
    bf16x8 b0 = *(const bf16x8*)(Bb_); \
    bf16x8 b1 = *(const bf16x8*)(Bb_ + 1024); \
    bf16x8 b2 = *(const bf16x8*)(Bb_ + 2048); \
    bf16x8 b3 = *(const bf16x8*)(Bb_ + 3072); \
    STAGE_; \
    __builtin_amdgcn_s_barrier(); \
    __builtin_amdgcn_s_setprio(1); \
    acc[(mh_)*4+0][0] = MF(a0, b0, acc[(mh_)*4+0][0]); \
    acc[(mh_)*4+0][1] = MF(a0, b1, acc[(mh_)*4+0][1]); \
    acc[(mh_)*4+0][2] = MF(a0, b2, acc[(mh_)*4+0][2]); \
    acc[(mh_)*4+0][3] = MF(a0, b3, acc[(mh_)*4+0][3]); \
    acc[(mh_)*4+1][0] = MF(a1, b0, acc[(mh_)*4+1][0]); \
    acc[(mh_)*4+1][1] = MF(a1, b1, acc[(mh_)*4+1][1]); \
    acc[(mh_)*4+1][2] = MF(a1, b2, acc[(mh_)*4+1][2]); \
    acc[(mh_)*4+1][3] = MF(a1, b3, acc[(mh_)*4+1][3]); \
    acc[(mh_)*4+2][0] = MF(a2, b0, acc[(mh_)*4+2][0]); \
    acc[(mh_)*4+2][1] = MF(a2, b1, acc[(mh_)*4+2][1]); \
    acc[(mh_)*4+2][2] = MF(a2, b2, acc[(mh_)*4+2][2]); \
    acc[(mh_)*4+2][3] = MF(a2, b3, acc[(mh_)*4+2][3]); \
    acc[(mh_)*4+3][0] = MF(a3, b0, acc[(mh_)*4+3][0]); \
    acc[(mh_)*4+3][1] = MF(a3, b1, acc[(mh_)*4+3][1]); \
    acc[(mh_)*4+3][2] = MF(a3, b2, acc[(mh_)*4+3][2]); \
    acc[(mh_)*4+3][3] = MF(a3, b3, acc[(mh_)*4+3][3]); \
    __builtin_amdgcn_s_setprio(0); \
    GATE_; \
    __builtin_amdgcn_s_barrier(); \
  } while (0)

__global__ __launch_bounds__(512, 1) void k_gemm(
    const unsigned short* __restrict__ A,   // [NS][DD] bf16
    const unsigned short* __restrict__ B,   // [CP][DD] bf16
    unsigned short* __restrict__ Dout) {    // [NS][CP] bf16
  __shared__ unsigned short lds[65536];     // 128 KiB
  char* ldsB = (char*)lds;
  int tid = threadIdx.x, lane = tid & 63, wid = tid >> 6;
  int wr = wid >> 2, wc = wid & 3;
  int bid = (blockIdx.x & 7) * 64 + (blockIdx.x >> 3);   // T1 bijective (512%8==0)
  int cb = bid & 3, rb = bid >> 2;
  int brow = rb * 256, bcol = cb * 256;

  f32x4 acc[8][4];
#pragma unroll
  for (int m = 0; m < 8; ++m)
#pragma unroll
    for (int n = 0; n < 4; ++n) acc[m][n] = (f32x4){0.f, 0.f, 0.f, 0.f};

  // staging: chunk = 128 rows x 32 k (8 KB) = one GLL16 (512 x 16B).
  // thread f: row = f>>2, phys granule f&3 holds logical granule
  // gl = (f&3)^((f>>3)&3) (inverse swizzle on the global source; rule #21).
  int f = tid;
  int gl = (f & 3) ^ ((f >> 3) & 3);
  const unsigned short* gA0 = A + (size_t)(brow + (f >> 2)) * DD + gl * 8;
  const unsigned short* gA1 = gA0 + (size_t)128 * DD;
  const unsigned short* gB0 = B + (size_t)(bcol + (f >> 2)) * DD + gl * 8;
  const unsigned short* gB1 = gB0 + (size_t)128 * DD;
  int dst = f * 16;                     // linear LDS dest within chunk

  // ds_read: local row lr = (lane&15) within frag, granule g = lane>>4,
  // byte = lr*64 + (g ^ ((lane>>1)&3))*16   (XOR matches stage side).
  int aoff = (lane & 15) * 64 + (((lane >> 4) ^ ((lane >> 1) & 3)) * 16);

  // prologue: stage tile 0 (kh0 then kh1); land kh0, keep kh1 in flight.
  SAK(0, 0); SBK(0, 0);
  SAK(0, 1); SBK(0, 1);
  VM4;
  __builtin_amdgcn_s_barrier();

#pragma unroll 1
  for (int t = 0; t < 15; ++t) {
    PHASE(t, 0, 0, SAK(t + 1, 0), (void)0);
    PHASE(t, 0, 1, SBK(t + 1, 0), VM4);
    PHASE(t, 1, 0, SAK(t + 1, 1), (void)0);
    PHASE(t, 1, 1, SBK(t + 1, 1), VM4);
  }
  PHASE(15, 0, 0, (void)0, (void)0);
  PHASE(15, 0, 1, (void)0, VM0);        // land tile 15 kh1
  PHASE(15, 1, 0, (void)0, (void)0);
  PHASE(15, 1, 1, (void)0, (void)0);

  // epilogue: C/D layout col=lane&15, row=(lane>>4)*4+j
  int colb = bcol + wc * 64 + (lane & 15);
  int rowb = brow + wr * 128 + ((lane >> 4) << 2);
#pragma unroll
  for (int m = 0; m < 8; ++m)
#pragma unroll
    for (int n = 0; n < 4; ++n)
#pragma unroll
      for (int j = 0; j < 4; ++j)
        Dout[(size_t)(rowb + m * 16 + j) * CP + colb + n * 16] = f2bf(acc[m][n][j]);
}

// ---------------- row max-softmax prob ------------------------------------
__global__ __launch_bounds__(256) void k_score(
    const float* __restrict__ P, float* __restrict__ scores) {
  int i = blockIdx.x, tid = threadIdx.x;
  const float* row = P + (size_t)i * NC;
  bool act = tid < 250;                 // 250*4 = 1000
  float p0 = 0, p1 = 0, p2 = 0, p3 = 0, mx = -1e30f;
  if (act) {
    int b = tid * 4;
    p0 = row[b]; p1 = row[b + 1]; p2 = row[b + 2]; p3 = row[b + 3];
    mx = fmaxf(fmaxf(p0, p1), fmaxf(p2, p3));
  }
  for (int off = 32; off; off >>= 1) mx = fmaxf(mx, __shfl_xor(mx, off));
  __shared__ float wmax[4];
  __shared__ double wsum[4];
  int lane = tid & 63, wid = tid >> 6;
  if (!lane) wmax[wid] = mx;
  __syncthreads();
  float m = fmaxf(fmaxf(wmax[0], wmax[1]), fmaxf(wmax[2], wmax[3]));
  double s = 0.0;
  if (act)
    s = (double)__expf(p0 - m) + (double)__expf(p1 - m) +
        (double)__expf(p2 - m) + (double)__expf(p3 - m);
  for (int off = 32; off; off >>= 1) s += __shfl_xor(s, off);
  if (!lane) wsum[wid] = s;
  __syncthreads();
  if (!tid) scores[i] = (float)(1.0 / (wsum[0] + wsum[1] + wsum[2] + wsum[3]));
}

// ---------------- per-row argmax (+ fp64 margin refine) -------------------
__global__ __launch_bounds__(256) void k_argmax(
    const unsigned short* __restrict__ Dot, const float* __restrict__ invc,
    const float* __restrict__ cnorm2, const float* __restrict__ feat,
    const float* __restrict__ cent, float* __restrict__ label_out,
    int* __restrict__ lidx) {
  __shared__ float s_inv[CP], s_cn[CP];
  int tid = threadIdx.x;
#pragma unroll
  for (int q = 0; q < 4; ++q) {
    int c = q * 256 + tid;
    s_inv[c] = invc[c]; s_cn[c] = cnorm2[c];
  }
  __syncthreads();
  int lane = tid & 63, wid = tid >> 6;
  int i = blockIdx.x * 4 + wid;
  const unsigned short* drow = Dot + (size_t)i * CP;

  float v[16];
  float dmax = -1e30f; int darg = CP;
  float emin = 1e30f;  int earg = CP;
#pragma unroll
  for (int it = 0; it < 16; ++it) {
    int c = it * 64 + lane;
    float val, ev;
    if (c < NC) {
      float d = bf2f(drow[c]);
      val = d * s_inv[c];
      ev = s_cn[c] - 2.0f * d;
    } else { val = -1e30f; ev = 1e30f; }
    v[it] = val;
    if (val > dmax) { dmax = val; darg = c; }   // per-lane c ascending -> first idx
    if (ev < emin)  { emin = ev;  earg = c; }
  }
  for (int off = 32; off; off >>= 1) {
    float om = __shfl_xor(dmax, off); int oi = __shfl_xor(darg, off);
    if (om > dmax || (om == dmax && oi < darg)) { dmax = om; darg = oi; }
    float oe = __shfl_xor(emin, off); int oj = __shfl_xor(earg, off);
    if (oe < emin || (oe == emin && oj < earg)) { emin = oe; earg = oj; }
  }
  // margin-certified candidates (val scale; bf16 GEMM + bf16 store err << 0.15)
  const float MARGIN = 0.15f;
  unsigned long long cmask[16]; int ccnt = 0;
#pragma unroll
  for (int it = 0; it < 16; ++it) {
    int c = it * 64 + lane;
    bool cand = (c < NC) && (v[it] >= dmax - MARGIN);
    cmask[it] = __ballot(cand);
    ccnt += __popcll(cmask[it]);
  }
  int finalArg = darg;
  double cosmax_d = -2.0;
  bool need = (ccnt > 1) || (dmax > 10.0f);
  if (need) {
    float xv[16]; double sx = 0.0;
    const float* xr = feat + (size_t)i * DD;
#pragma unroll
    for (int t = 0; t < 16; ++t) {
      float x = xr[t * 64 + lane]; xv[t] = x; sx += (double)x * (double)x;
    }
    for (int off = 32; off; off >>= 1) sx += __shfl_xor(sx, off);
    double nx = sqrt(sx); if (nx < 1e-8) nx = 1e-8;
    double best = -2.0; int besti = CP;
    for (int it = 0; it < 16; ++it) {
      unsigned long long mk = cmask[it];   // wave-uniform
      while (mk) {
        int b = __builtin_ctzll(mk); mk &= mk - 1;
        int c = it * 64 + b;
        const float* cr = cent + (size_t)c * DD;
        double s = 0.0, s2 = 0.0;
#pragma unroll
        for (int t = 0; t < 16; ++t) {
          double cv = (double)cr[t * 64 + lane];
          s += (double)xv[t] * cv; s2 += cv * cv;
        }
        for (int off = 32; off; off >>= 1) {
          s += __shfl_xor(s, off); s2 += __shfl_xor(s2, off);
        }
        double nc = sqrt(s2); if (nc < 1e-8) nc = 1e-8;
        double cs = s / (nx * nc);
        if (cs > best) { best = cs; besti = c; }   // ascending c => first idx
      }
    }
    finalArg = besti; cosmax_d = best;
  }
  if (!lane) {
    lidx[i] = finalArg;
    float lab = -1.0f;
    // non-refined rows: cos <= dmax/16 <= 0.625 < 0.85 (nx >= 16 whp; else need fired)
    if (need && finalArg == earg && cosmax_d > 0.85) lab = (float)finalArg;
    label_out[i] = lab;
  }
}

// ---------------- top-K scatter replay: one class per block (1 wave) ------
__global__ __launch_bounds__(64) void k_scan(
    const int* __restrict__ lidx, const float* __restrict__ scores,
    const int* __restrict__ uidx, const float* __restrict__ ptn_in,
    const int* __restrict__ fidx_in, float* __restrict__ out_ptn,
    float* __restrict__ out_fidx) {
  int c = blockIdx.x;                // class id, 0..NC-1
  int lane = threadIdx.x;
  float row[KN]; int idx[KN];
#pragma unroll
  for (int j = 0; j < KN; ++j) {
    row[j] = ptn_in[c * KN + j];
    idx[j] = fidx_in[c * KN + j];
  }
  for (int base = 0; base < NS; base += 256) {
    int l0 = lidx[base + lane];
    int l1 = lidx[base + 64 + lane];
    int l2 = lidx[base + 128 + lane];
    int l3 = lidx[base + 192 + lane];
#pragma unroll
    for (int q = 0; q < 4; ++q) {
      int lab = (q == 0) ? l0 : (q == 1) ? l1 : (q == 2) ? l2 : l3;
      unsigned long long m = __ballot(lab == c);
      while (m) {                        // wave-uniform mask -> no divergence
        int b = __builtin_ctzll(m); m &= m - 1;
        int i = base + q * 64 + b;       // ascending i order
        float s = scores[i];             // uniform addr -> scalar load
        int ui = uidx[i];
        int mi = 0; float mn = row[0];
#pragma unroll
        for (int t = 1; t < KN; ++t)
          if (row[t] < mn) { mn = row[t]; mi = t; }   // strict < => first idx
        if (s > mn) {                                 // strict > per reference
#pragma unroll
          for (int t = 0; t < KN; ++t)
            if (t == mi) { row[t] = s; idx[t] = ui; } // static idx, stays in regs
        }
      }
    }
  }
  if (!lane) {
#pragma unroll
    for (int j = 0; j < KN; ++j) {
      out_ptn[c * KN + j] = row[j];
      out_fidx[c * KN + j] = (float)idx[j];
    }
  }
}

extern "C" void kernel_launch(void* const* d_in, const int* in_sizes, int n_in,
                              void* d_out, int out_size, void* d_ws, size_t ws_size,
                              hipStream_t stream) {
  const float* feature = (const float*)d_in[0];
  const float* pred    = (const float*)d_in[1];
  const int*   uidx    = (const int*)d_in[2];
  const float* cent    = (const float*)d_in[3];
  const float* ptn_in  = (const float*)d_in[4];
  const int*   fidx_in = (const int*)d_in[5];
  float* out = (float*)d_out;

  char* ws = (char*)d_ws;
  unsigned short* cent_bf = (unsigned short*)(ws);                              // 2 MiB
  unsigned short* feat_bf = (unsigned short*)(ws + (2ull << 20));               // 64 MiB
  unsigned short* dot_bf  = (unsigned short*)(ws + (66ull << 20));              // 64 MiB
  float* scores = (float*)(ws + (130ull << 20));                                // 128 KiB
  int*   lidx   = (int*)  (ws + (130ull << 20) + (128ull << 10));               // 128 KiB
  float* cnorm2 = (float*)(ws + (130ull << 20) + (256ull << 10));               // 4 KiB
  float* invc   = (float*)(ws + (130ull << 20) + (260ull << 10));               // 4 KiB

  hipLaunchKernelGGL(k_cast_cent, dim3(CP), dim3(256), 0, stream,
                     cent, cent_bf, cnorm2, invc);
  hipLaunchKernelGGL(k_cast_feat, dim3((NS * DD / 8) / 256), dim3(256), 0, stream,
                     feature, feat_bf);
  hipLaunchKernelGGL(k_gemm, dim3((NS / 256) * (CP / 256)), dim3(512), 0, stream,
                     feat_bf, cent_bf, dot_bf);
  hipLaunchKernelGGL(k_score, dim3(NS), dim3(256), 0, stream, pred, scores);
  hipLaunchKernelGGL(k_argmax, dim3(NS / 4), dim3(256), 0, stream,
                     dot_bf, invc, cnorm2, feature, cent, out, lidx);
  hipLaunchKernelGGL(k_scan, dim3(NC), dim3(64), 0, stream,
                     lidx, scores, uidx, ptn_in, fidx_in,
                     out + NS, out + NS + NC * KN);
}

// Round 9
// 224.522 us; speedup vs baseline: 1.0692x; 1.0692x over previous
//
#include <hip/hip_runtime.h>
#include <hip/hip_bf16.h>
#include <math.h>

#define NS 32768   // samples
#define NC 1000    // classes
#define CP 1024    // padded classes
#define DD 1024    // feature dim
#define KN 16      // KNN

typedef __attribute__((ext_vector_type(8))) short bf16x8;
typedef __attribute__((ext_vector_type(4))) float f32x4;
typedef __attribute__((ext_vector_type(4))) float float4v;
typedef __attribute__((ext_vector_type(4))) int int4v;
typedef __attribute__((ext_vector_type(8))) unsigned short u16x8;
typedef __attribute__((ext_vector_type(4))) unsigned short u16x4;

__device__ __forceinline__ unsigned short f2bf(float f) {
  unsigned u = __float_as_uint(f);
  u += 0x7FFFu + ((u >> 16) & 1u);          // RNE
  return (unsigned short)(u >> 16);
}
__device__ __forceinline__ float bf2f(unsigned short h) {
  return __uint_as_float(((unsigned)h) << 16);
}

#define GLL16(g, l) __builtin_amdgcn_global_load_lds( \
    (const __attribute__((address_space(1))) void*)(g), \
    (__attribute__((address_space(3))) void*)(l), 16, 0, 0)

// ---------------- fused prep: score (softmax-max) / cast feat / cast cent --
// Three independent BW-bound passes merged into one dispatch: blocks
// [0,NS) = score rows, [NS, NS+16384) = feature cast, last 1024 = cent cast.
#define PREP_FEAT_BLKS (NS * DD / 8 / 256)
__global__ __launch_bounds__(256) void k_prep(
    const float* __restrict__ Cm, unsigned short* __restrict__ Cb,
    float* __restrict__ cnorm2, float* __restrict__ invc,
    const float* __restrict__ A, unsigned short* __restrict__ Ab,
    const float* __restrict__ P, float* __restrict__ scores) {
  __shared__ float red[4];
  __shared__ float wmax[4];
  __shared__ double wsum[4];
  int b = blockIdx.x, tid = threadIdx.x;
  int lane = tid & 63, wid = tid >> 6;
  if (b < NS) {
    // ---- score: max softmax prob of pred row b
    const float* row = P + (size_t)b * NC;
    bool act = tid < 250;                 // 250*4 = 1000
    float p0 = 0, p1 = 0, p2 = 0, p3 = 0, mx = -1e30f;
    if (act) {
      int o = tid * 4;
      p0 = row[o]; p1 = row[o + 1]; p2 = row[o + 2]; p3 = row[o + 3];
      mx = fmaxf(fmaxf(p0, p1), fmaxf(p2, p3));
    }
    for (int off = 32; off; off >>= 1) mx = fmaxf(mx, __shfl_xor(mx, off));
    if (!lane) wmax[wid] = mx;
    __syncthreads();
    float m = fmaxf(fmaxf(wmax[0], wmax[1]), fmaxf(wmax[2], wmax[3]));
    double s = 0.0;
    if (act)
      s = (double)__expf(p0 - m) + (double)__expf(p1 - m) +
          (double)__expf(p2 - m) + (double)__expf(p3 - m);
    for (int off = 32; off; off >>= 1) s += __shfl_xor(s, off);
    if (!lane) wsum[wid] = s;
    __syncthreads();
    if (!tid) scores[b] = (float)(1.0 / (wsum[0] + wsum[1] + wsum[2] + wsum[3]));
  } else if (b < NS + PREP_FEAT_BLKS) {
    // ---- cast feature -> bf16 (8 elems/thread)
    int t = (b - NS) * 256 + tid;
    const float4v* src = (const float4v*)A + (size_t)t * 2;
    float4v a = src[0], v = src[1];
    u16x8 o = { f2bf(a[0]), f2bf(a[1]), f2bf(a[2]), f2bf(a[3]),
                f2bf(v[0]), f2bf(v[1]), f2bf(v[2]), f2bf(v[3]) };
    *(u16x8*)(Ab + (size_t)t * 8) = o;
  } else {
    // ---- cast centroids -> bf16 (padded to 1024 rows) + norms
    int c = b - NS - PREP_FEAT_BLKS;      // 0..1023
    float sq = 0.f;
    if (c < NC) {
      float4v v = ((const float4v*)(Cm + (size_t)c * DD))[tid];
      sq = v[0]*v[0] + v[1]*v[1] + v[2]*v[2] + v[3]*v[3];
      u16x4 o = { f2bf(v[0]), f2bf(v[1]), f2bf(v[2]), f2bf(v[3]) };
      *(u16x4*)(Cb + (size_t)c * DD + tid * 4) = o;
    } else {
      u16x4 z = { 0, 0, 0, 0 };
      *(u16x4*)(Cb + (size_t)c * DD + tid * 4) = z;
    }
    for (int off = 32; off; off >>= 1) sq += __shfl_xor(sq, off);
    if (!lane) red[wid] = sq;
    __syncthreads();
    if (!tid) {
      float s = red[0] + red[1] + red[2] + red[3];
      cnorm2[c] = s;
      float n = sqrtf(s); if (n < 1e-8f) n = 1e-8f;
      invc[c] = (c < NC) ? 1.0f / n : 0.0f;
    }
  }
}

// ---------------- GEMM: dot[i][c] = sum_k feat[i,k]*cent[c,k]  (bf16) -----
// R7 version (verified 80.8us): 256x256 tile, BK=32, 8 waves, 512 threads,
// 4 LDS buffers, all-global_load_lds staging, ONE raw s_barrier per K-step,
// counted vmcnt(4). T1 XCD swizzle, T2 granule-XOR (conflicts=0), T5 setprio.
#define MF(a_, b_, c_) __builtin_amdgcn_mfma_f32_16x16x32_bf16(a_, b_, c_, 0, 0, 0)
#define RD(base_, i_) (*(const bf16x8*)((base_) + (i_) * 1024 + aoff))
#define SA(s_, b_) do { \
    GLL16(pA0 + (s_) * 32, ldsB + (b_) * 16384 + dA0); \
    GLL16(pA1 + (s_) * 32, ldsB + (b_) * 16384 + dA1); } while (0)
#define SB(s_, b_) do { \
    GLL16(pB0 + (s_) * 32, ldsB + 65536 + (b_) * 16384 + dA0); \
    GLL16(pB1 + (s_) * 32, ldsB + 65536 + (b_) * 16384 + dA1); } while (0)
#define VM4 asm volatile("s_waitcnt vmcnt(4)" ::: "memory")
#define VM0 asm volatile("s_waitcnt vmcnt(0)" ::: "memory")
#define MFMAC(A0_, A1_, A2_, A3_, M0) do { \
    acc[M0+0][0] = MF(A0_, bv0, acc[M0+0][0]); \
    acc[M0+0][1] = MF(A0_, bv1, acc[M0+0][1]); \
    acc[M0+0][2] = MF(A0_, bv2, acc[M0+0][2]); \
    acc[M0+0][3] = MF(A0_, bv3, acc[M0+0][3]); \
    acc[M0+1][0] = MF(A1_, bv0, acc[M0+1][0]); \
    acc[M0+1][1] = MF(A1_, bv1, acc[M0+1][1]); \
    acc[M0+1][2] = MF(A1_, bv2, acc[M0+1][2]); \
    acc[M0+1][3] = MF(A1_, bv3, acc[M0+1][3]); \
    acc[M0+2][0] = MF(A2_, bv0, acc[M0+2][0]); \
    acc[M0+2][1] = MF(A2_, bv1, acc[M0+2][1]); \
    acc[M0+2][2] = MF(A2_, bv2, acc[M0+2][2]); \
    acc[M0+2][3] = MF(A2_, bv3, acc[M0+2][3]); \
    acc[M0+3][0] = MF(A3_, bv0, acc[M0+3][0]); \
    acc[M0+3][1] = MF(A3_, bv1, acc[M0+3][1]); \
    acc[M0+3][2] = MF(A3_, bv2, acc[M0+3][2]); \
    acc[M0+3][3] = MF(A3_, bv3, acc[M0+3][3]); } while (0)
#define KSTEP(s_, STAGE_, GATE_) do { \
    const char* Ab_ = ldsB + ((s_) & 3) * 16384 + wrOff; \
    const char* Bb_ = ldsB + 65536 + ((s_) & 3) * 16384 + wcOff; \
    af0 = RD(Ab_, 0); af1 = RD(Ab_, 1); af2 = RD(Ab_, 2); af3 = RD(Ab_, 3); \
    bv0 = RD(Bb_, 0); bv1 = RD(Bb_, 1); bv2 = RD(Bb_, 2); bv3 = RD(Bb_, 3); \
    af4 = RD(Ab_, 4); af5 = RD(Ab_, 5); af6 = RD(Ab_, 6); af7 = RD(Ab_, 7); \
    STAGE_; \
    __builtin_amdgcn_s_setprio(1); \
    MFMAC(af0, af1, af2, af3, 0); \
    MFMAC(af4, af5, af6, af7, 4); \
    __builtin_amdgcn_s_setprio(0); \
    GATE_; \
    __builtin_amdgcn_s_barrier(); \
  } while (0)

__global__ __launch_bounds__(512, 1) void k_gemm(
    const unsigned short* __restrict__ A,   // [NS][DD] bf16
    const unsigned short* __restrict__ B,   // [CP][DD] bf16
    unsigned short* __restrict__ Dout) {    // [NS][CP] bf16
  __shared__ unsigned short lds[65536];     // 128 KiB: A bufs @0, B bufs @64KB
  char* ldsB = (char*)lds;
  int tid = threadIdx.x, lane = tid & 63, wid = tid >> 6;
  int wr = wid >> 2, wc = wid & 3;
  int bid = (blockIdx.x & 7) * 64 + (blockIdx.x >> 3);   // T1 bijective (512%8==0)
  int cb = bid & 3, rb = bid >> 2;
  int brow = rb * 256, bcol = cb * 256;

  f32x4 acc[8][4];
#pragma unroll
  for (int m = 0; m < 8; ++m)
#pragma unroll
    for (int n = 0; n < 4; ++n) acc[m][n] = (f32x4){0.f, 0.f, 0.f, 0.f};

  // staging: panel = 256 rows x 32 k (16 KB) = 1024 granules of 16B;
  // physical granule (row,pg) holds logical k-granule gl = pg ^ ((row>>1)&3)
  // (inverse-swizzled global source; rule #21 both-sides involution).
  int f0 = wid * 64 + lane, f1 = f0 + 512;
  int gl0 = (f0 & 3) ^ ((f0 >> 3) & 3);
  int gl1 = (f1 & 3) ^ ((f1 >> 3) & 3);
  const unsigned short* pA0 = A + (size_t)(brow + (f0 >> 2)) * DD + gl0 * 8;
  const unsigned short* pA1 = A + (size_t)(brow + (f1 >> 2)) * DD + gl1 * 8;
  const unsigned short* pB0 = B + (size_t)(bcol + (f0 >> 2)) * DD + gl0 * 8;
  const unsigned short* pB1 = B + (size_t)(bcol + (f1 >> 2)) * DD + gl1 * 8;
  int dA0 = f0 * 16, dA1 = f1 * 16;   // linear LDS dest (16B granules)

  // ds_read: row = fragbase + (lane&15), k-granule g = lane>>4,
  // byte = row*64 + (g ^ ((lane>>1)&3))*16.
  int aoff = (lane & 15) * 64 + (((lane >> 4) ^ ((lane >> 1) & 3)) * 16);
  int wrOff = wr * 8192;    // A: 128 rows per wr
  int wcOff = wc * 4096;    // B: 64 rows per wc

  bf16x8 af0, af1, af2, af3, af4, af5, af6, af7, bv0, bv1, bv2, bv3;

  // prologue: stage steps 0,1; land step 0 (leave step 1's 4 in flight).
  SA(0, 0); SB(0, 0);
  SA(1, 1); SB(1, 1);
  VM4;
  __builtin_amdgcn_s_barrier();

  for (int s = 0; s < 30; ++s) {
    int bn = (s + 2) & 3;
    KSTEP(s, { SA(s + 2, bn); SB(s + 2, bn); }, VM4);
  }
  KSTEP(30, (void)0, VM0);        // drain step 31's loads
  KSTEP(31, (void)0, (void)0);

  // epilogue: C/D layout col=lane&15, row=(lane>>4)*4+j
  int colb = bcol + wc * 64 + (lane & 15);
  int rowb = brow + wr * 128 + ((lane >> 4) << 2);
#pragma unroll
  for (int m = 0; m < 8; ++m)
#pragma unroll
    for (int n = 0; n < 4; ++n)
#pragma unroll
      for (int j = 0; j < 4; ++j)
        Dout[(size_t)(rowb + m * 16 + j) * CP + colb + n * 16] = f2bf(acc[m][n][j]);
}

// ---------------- per-row argmax (+ fp64 margin refine) -------------------
__global__ __launch_bounds__(256) void k_argmax(
    const unsigned short* __restrict__ Dot, const float* __restrict__ invc,
    const float* __restrict__ cnorm2, const float* __restrict__ feat,
    const float* __restrict__ cent, float* __restrict__ label_out,
    int* __restrict__ lidx) {
  __shared__ float s_inv[CP], s_cn[CP];
  int tid = threadIdx.x;
#pragma unroll
  for (int q = 0; q < 4; ++q) {
    int c = q * 256 + tid;
    s_inv[c] = invc[c]; s_cn[c] = cnorm2[c];
  }
  __syncthreads();
  int lane = tid & 63, wid = tid >> 6;
  int i = blockIdx.x * 4 + wid;
  const unsigned short* drow = Dot + (size_t)i * CP;

  float v[16];
  float dmax = -1e30f; int darg = CP;
  float emin = 1e30f;  int earg = CP;
#pragma unroll
  for (int it = 0; it < 16; ++it) {
    int c = it * 64 + lane;
    float val, ev;
    if (c < NC) {
      float d = bf2f(drow[c]);
      val = d * s_inv[c];
      ev = s_cn[c] - 2.0f * d;
    } else { val = -1e30f; ev = 1e30f; }
    v[it] = val;
    if (val > dmax) { dmax = val; darg = c; }   // per-lane c ascending -> first idx
    if (ev < emin)  { emin = ev;  earg = c; }
  }
  for (int off = 32; off; off >>= 1) {
    float om = __shfl_xor(dmax, off); int oi = __shfl_xor(darg, off);
    if (om > dmax || (om == dmax && oi < darg)) { dmax = om; darg = oi; }
    float oe = __shfl_xor(emin, off); int oj = __shfl_xor(earg, off);
    if (oe < emin || (oe == emin && oj < earg)) { emin = oe; earg = oj; }
  }
  // margin-certified candidates (val scale; bf16 GEMM + bf16 store err << 0.15)
  const float MARGIN = 0.15f;
  unsigned long long cmask[16]; int ccnt = 0;
#pragma unroll
  for (int it = 0; it < 16; ++it) {
    int c = it * 64 + lane;
    bool cand = (c < NC) && (v[it] >= dmax - MARGIN);
    cmask[it] = __ballot(cand);
    ccnt += __popcll(cmask[it]);
  }
  int finalArg = darg;
  double cosmax_d = -2.0;
  bool need = (ccnt > 1) || (dmax > 10.0f);
  if (need) {
    float xv[16]; double sx = 0.0;
    const float* xr = feat + (size_t)i * DD;
#pragma unroll
    for (int t = 0; t < 16; ++t) {
      float x = xr[t * 64 + lane]; xv[t] = x; sx += (double)x * (double)x;
    }
    for (int off = 32; off; off >>= 1) sx += __shfl_xor(sx, off);
    double nx = sqrt(sx); if (nx < 1e-8) nx = 1e-8;
    double best = -2.0; int besti = CP;
    for (int it = 0; it < 16; ++it) {
      unsigned long long mk = cmask[it];   // wave-uniform
      while (mk) {
        int b = __builtin_ctzll(mk); mk &= mk - 1;
        int c = it * 64 + b;
        const float* cr = cent + (size_t)c * DD;
        double s = 0.0, s2 = 0.0;
#pragma unroll
        for (int t = 0; t < 16; ++t) {
          double cv = (double)cr[t * 64 + lane];
          s += (double)xv[t] * cv; s2 += cv * cv;
        }
        for (int off = 32; off; off >>= 1) {
          s += __shfl_xor(s, off); s2 += __shfl_xor(s2, off);
        }
        double nc = sqrt(s2); if (nc < 1e-8) nc = 1e-8;
        double cs = s / (nx * nc);
        if (cs > best) { best = cs; besti = c; }   // ascending c => first idx
      }
    }
    finalArg = besti; cosmax_d = best;
  }
  if (!lane) {
    lidx[i] = finalArg;
    float lab = -1.0f;
    // non-refined rows: cos <= dmax/16 <= 0.625 < 0.85 (nx >= 16 whp; else need fired)
    if (need && finalArg == earg && cosmax_d > 0.85) lab = (float)finalArg;
    label_out[i] = lab;
  }
}

// ---------------- top-K scatter replay: one class per block (1 wave) ------
__global__ __launch_bounds__(64) void k_scan(
    const int* __restrict__ lidx, const float* __restrict__ scores,
    const int* __restrict__ uidx, const float* __restrict__ ptn_in,
    const int* __restrict__ fidx_in, float* __restrict__ out_ptn,
    float* __restrict__ out_fidx) {
  int c = blockIdx.x;                // class id, 0..NC-1
  int lane = threadIdx.x;
  float row[KN]; int idx[KN];
#pragma unroll
  for (int j = 0; j < KN; ++j) {
    row[j] = ptn_in[c * KN + j];
    idx[j] = fidx_in[c * KN + j];
  }
  for (int base = 0; base < NS; base += 256) {
    int l0 = lidx[base + lane];
    int l1 = lidx[base + 64 + lane];
    int l2 = lidx[base + 128 + lane];
    int l3 = lidx[base + 192 + lane];
#pragma unroll
    for (int q = 0; q < 4; ++q) {
      int lab = (q == 0) ? l0 : (q == 1) ? l1 : (q == 2) ? l2 : l3;
      unsigned long long m = __ballot(lab == c);
      while (m) {                        // wave-uniform mask -> no divergence
        int b = __builtin_ctzll(m); m &= m - 1;
        int i = base + q * 64 + b;       // ascending i order
        float s = scores[i];             // uniform addr -> scalar load
        int ui = uidx[i];
        int mi = 0; float mn = row[0];
#pragma unroll
        for (int t = 1; t < KN; ++t)
          if (row[t] < mn) { mn = row[t]; mi = t; }   // strict < => first idx
        if (s > mn) {                                 // strict > per reference
#pragma unroll
          for (int t = 0; t < KN; ++t)
            if (t == mi) { row[t] = s; idx[t] = ui; } // static idx, stays in regs
        }
      }
    }
  }
  if (!lane) {
#pragma unroll
    for (int j = 0; j < KN; ++j) {
      out_ptn[c * KN + j] = row[j];
      out_fidx[c * KN + j] = (float)idx[j];
    }
  }
}

extern "C" void kernel_launch(void* const* d_in, const int* in_sizes, int n_in,
                              void* d_out, int out_size, void* d_ws, size_t ws_size,
                              hipStream_t stream) {
  const float* feature = (const float*)d_in[0];
  const float* pred    = (const float*)d_in[1];
  const int*   uidx    = (const int*)d_in[2];
  const float* cent    = (const float*)d_in[3];
  const float* ptn_in  = (const float*)d_in[4];
  const int*   fidx_in = (const int*)d_in[5];
  float* out = (float*)d_out;

  char* ws = (char*)d_ws;
  unsigned short* cent_bf = (unsigned short*)(ws);                              // 2 MiB
  unsigned short* feat_bf = (unsigned short*)(ws + (2ull << 20));               // 64 MiB
  unsigned short* dot_bf  = (unsigned short*)(ws + (66ull << 20));              // 64 MiB
  float* scores = (float*)(ws + (130ull << 20));                                // 128 KiB
  int*   lidx   = (int*)  (ws + (130ull << 20) + (128ull << 10));               // 128 KiB
  float* cnorm2 = (float*)(ws + (130ull << 20) + (256ull << 10));               // 4 KiB
  float* invc   = (float*)(ws + (130ull << 20) + (260ull << 10));               // 4 KiB

  hipLaunchKernelGGL(k_prep, dim3(NS + PREP_FEAT_BLKS + CP), dim3(256), 0, stream,
                     cent, cent_bf, cnorm2, invc,
                     feature, feat_bf, pred, scores);
  hipLaunchKernelGGL(k_gemm, dim3((NS / 256) * (CP / 256)), dim3(512), 0, stream,
                     feat_bf, cent_bf, dot_bf);
  hipLaunchKernelGGL(k_argmax, dim3(NS / 4), dim3(256), 0, stream,
                     dot_bf, invc, cnorm2, feature, cent, out, lidx);
  hipLaunchKernelGGL(k_scan, dim3(NC), dim3(64), 0, stream,
                     lidx, scores, uidx, ptn_in, fidx_in,
                     out + NS, out + NS + NC * KN);
}